// Round 1
// baseline (2620.877 us; speedup 1.0000x reference)
//
#include <hip/hip_runtime.h>
#include <math.h>

#define CIN 32
#define COUT 32
#define NB 16
#define IMG 256
#define GH 16
#define EPSV 1e-5f

__device__ __forceinline__ float sigmoidf_(float v) { return 1.0f / (1.0f + __expf(-v)); }

// K0: transpose weights to [tap][out] layout so inner-o loop reads consecutive,
// wave-uniform addresses (scalar loads through K$).
__global__ __launch_bounds__(256) void transpose_w(const float* __restrict__ cw,
                                                   const float* __restrict__ gw,
                                                   float* __restrict__ wTc,
                                                   float* __restrict__ wTg) {
  int i = blockIdx.x * 256 + threadIdx.x;
  if (i < 9216) {                 // conv_w [o][c][3][3] -> [c*9+tap][o]
    int o = i / 288, rr = i % 288;
    wTc[rr * 32 + o] = cw[i];
  }
  if (i < 18432) {                // gate_w [o][ic][3][3] -> [ic*9+tap][o]
    int o = i / 576, rr = i % 576;
    wTg[rr * 32 + o] = gw[i];
  }
}

// K1: conv3x3+bias -> y ; fused per-patch mean -> nodes ; fused GN partial stats.
__global__ __launch_bounds__(256) void conv1_kernel(const float* __restrict__ x,
                                                    const float* __restrict__ wT,
                                                    const float* __restrict__ conv_b,
                                                    float* __restrict__ y,
                                                    float* __restrict__ stats,
                                                    float* __restrict__ nodes) {
  __shared__ float xt[CIN * 324];     // 32 x 18 x 18
  __shared__ float part[32][4];
  __shared__ float gpart[8][2][4];
  int blk = blockIdx.x;
  int b = blk >> 8, r = blk & 255, gy = r >> 4, gx = r & 15;
  int tid = threadIdx.x;
  int y0 = gy * 16 - 1, x0 = gx * 16 - 1;
  for (int i = tid; i < CIN * 324; i += 256) {
    int c = i / 324, rr = i % 324;
    int row = rr / 18, col = rr % 18;
    int yy = y0 + row, xx = x0 + col;
    float v = 0.f;
    if ((unsigned)yy < 256u && (unsigned)xx < 256u)
      v = x[((b * CIN + c) * 256 + yy) * 256 + xx];
    xt[i] = v;
  }
  __syncthreads();
  int py = tid >> 4, px = tid & 15;
  int wave = tid >> 6, lane = tid & 63;
  // patch means (interior 16x16 of the tile == the GraphBuilder patch)
  for (int c = 0; c < CIN; ++c) {
    float v = xt[c * 324 + (py + 1) * 18 + (px + 1)];
    for (int m = 32; m; m >>= 1) v += __shfl_xor(v, m);
    if (lane == 0) part[c][wave] = v;
  }
  __syncthreads();
  if (tid < 32) {
    float s = part[tid][0] + part[tid][1] + part[tid][2] + part[tid][3];
    nodes[blk * 34 + tid] = s * (1.0f / 256.0f);
  }
  if (tid == 32) nodes[blk * 34 + 32] = (float)gy * (1.0f / 16.0f);
  if (tid == 33) nodes[blk * 34 + 33] = (float)gx * (1.0f / 16.0f);
  // conv: each thread one pixel, all 32 out channels in registers
  float acc[COUT];
#pragma unroll
  for (int o = 0; o < COUT; ++o) acc[o] = conv_b[o];
  for (int c = 0; c < CIN; ++c) {
#pragma unroll
    for (int ky = 0; ky < 3; ++ky)
#pragma unroll
      for (int kx = 0; kx < 3; ++kx) {
        float v = xt[c * 324 + (py + ky) * 18 + (px + kx)];
        const float* wp = wT + (c * 9 + ky * 3 + kx) * 32;
#pragma unroll
        for (int o = 0; o < COUT; ++o) acc[o] = fmaf(v, wp[o], acc[o]);
      }
  }
  int oy = gy * 16 + py, ox = gx * 16 + px;
#pragma unroll
  for (int o = 0; o < COUT; ++o)
    y[((b * COUT + o) * 256 + oy) * 256 + ox] = acc[o];
  // GN partial stats per group (4 channels / group)
#pragma unroll
  for (int g = 0; g < 8; ++g) {
    float s = acc[4 * g] + acc[4 * g + 1] + acc[4 * g + 2] + acc[4 * g + 3];
    float q = acc[4 * g] * acc[4 * g] + acc[4 * g + 1] * acc[4 * g + 1] +
              acc[4 * g + 2] * acc[4 * g + 2] + acc[4 * g + 3] * acc[4 * g + 3];
    for (int m = 32; m; m >>= 1) { s += __shfl_xor(s, m); q += __shfl_xor(q, m); }
    if (lane == 0) { gpart[g][0][wave] = s; gpart[g][1][wave] = q; }
  }
  __syncthreads();
  if (tid < 16) {
    int g = tid >> 1, which = tid & 1;
    float s = gpart[g][which][0] + gpart[g][which][1] + gpart[g][which][2] + gpart[g][which][3];
    atomicAdd(&stats[(which ? 128 : 0) + b * 8 + g], s);
  }
}

// K2: GN mean/rstd
__global__ void gn_finalize(const float* __restrict__ stats, float* __restrict__ mr) {
  int i = threadIdx.x;  // 128 = 16*8
  float s = stats[i], q = stats[128 + i];
  const float n = (float)(4 * IMG * IMG);
  float mean = s / n;
  float var = q / n - mean * mean;
  mr[i] = mean;
  mr[128 + i] = rsqrtf(var + EPSV);
}

// K3: h = nodes @ gcn_w   (4096 x 34) @ (34 x 32)
__global__ __launch_bounds__(256) void gcn_mm(const float* __restrict__ nodes,
                                              const float* __restrict__ gw,
                                              float* __restrict__ h) {
  int idx = blockIdx.x * 256 + threadIdx.x;  // < 4096*32
  int n = idx >> 5, o = idx & 31;
  const float* nr = nodes + n * 34;
  float s = 0.f;
#pragma unroll
  for (int k = 0; k < 34; ++k) s = fmaf(nr[k], gw[k * 32 + o], s);
  h[idx] = s;
}

__device__ __forceinline__ float dinv_at(int gy, int gx) {
  return rsqrtf((float)(1 + (gy > 0) + (gy < 15) + (gx > 0) + (gx < 15)));
}

// K4: GCN propagation (analytic grid degrees) + bias + LayerNorm over channels
__global__ __launch_bounds__(64) void gcn_prop_ln(const float* __restrict__ h,
                                                  const float* __restrict__ gcn_b,
                                                  const float* __restrict__ ln_g,
                                                  const float* __restrict__ ln_b,
                                                  float* __restrict__ lnout) {
  int n = blockIdx.x * 2 + (threadIdx.x >> 5);
  int o = threadIdx.x & 31;
  int r = n & 255, gy = r >> 4, gx = r & 15;
  float dn = dinv_at(gy, gx);
  float s = h[n * 32 + o] * dn;  // self loop
  if (gy > 0)  s += h[(n - 16) * 32 + o] * dinv_at(gy - 1, gx);
  if (gy < 15) s += h[(n + 16) * 32 + o] * dinv_at(gy + 1, gx);
  if (gx > 0)  s += h[(n - 1) * 32 + o] * dinv_at(gy, gx - 1);
  if (gx < 15) s += h[(n + 1) * 32 + o] * dinv_at(gy, gx + 1);
  float g = dn * s + gcn_b[o];
  float mu = g;
  for (int m = 16; m; m >>= 1) mu += __shfl_xor(mu, m);
  mu *= (1.0f / 32.0f);
  float d = g - mu;
  float v = d * d;
  for (int m = 16; m; m >>= 1) v += __shfl_xor(v, m);
  v *= (1.0f / 32.0f);
  lnout[n * 32 + o] = d * rsqrtf(v + EPSV) * ln_g[o] + ln_b[o];
}

// K5: FiLM projection tp = t @ tp_w^T + tp_b  -> [16, 64]
__global__ __launch_bounds__(256) void tproj(const float* __restrict__ t,
                                             const float* __restrict__ tw,
                                             const float* __restrict__ tb,
                                             float* __restrict__ tp) {
  int idx = blockIdx.x * 256 + threadIdx.x;  // < 1024
  int b = idx >> 6, j = idx & 63;
  const float* tr = t + b * 256;
  const float* wr = tw + j * 256;
  float s = tb[j];
  for (int k = 0; k < 256; ++k) s = fmaf(tr[k], wr[k], s);
  tp[idx] = s;
}

// K6: fused GN+SiLU on load, bilinear upsample of scrambled-reshaped LN grid,
// gate conv 3x3 (64->32), sigmoid, merge, FiLM, store.
__global__ __launch_bounds__(256) void fused_gate(const float* __restrict__ ycv,
                                                  const float* __restrict__ mr,
                                                  const float* __restrict__ gn_g,
                                                  const float* __restrict__ gn_b,
                                                  const float* __restrict__ lnf,
                                                  const float* __restrict__ wTg,
                                                  const float* __restrict__ gate_b,
                                                  const float* __restrict__ tp,
                                                  float* __restrict__ out) {
  __shared__ float comb[64 * 324];  // 82,944 B: [0..31]=conv_feat, [32..63]=gcn_up
  int blk = blockIdx.x;
  int b = blk >> 8, r = blk & 255, gy = r >> 4, gx = r & 15;
  int tid = threadIdx.x;
  int y0 = gy * 16 - 1, x0 = gx * 16 - 1;
  // conv_feat half: GN + SiLU applied on load; zero outside image (SAME pad)
  for (int i = tid; i < 32 * 324; i += 256) {
    int c = i / 324, rr = i % 324;
    int row = rr / 18, col = rr % 18;
    int yy = y0 + row, xx = x0 + col;
    float v = 0.f;
    if ((unsigned)yy < 256u && (unsigned)xx < 256u) {
      v = ycv[((b * 32 + c) * 256 + yy) * 256 + xx];
      int g = c >> 2;
      v = (v - mr[b * 8 + g]) * mr[128 + b * 8 + g];
      v = v * gn_g[c] + gn_b[c];
      v = v * sigmoidf_(v);
    }
    comb[i] = v;
  }
  // gcn_up half: bilinear (align_corners=False, edge-renormalized == clamped)
  // grid value G(b,c,gy,gx) = lnf[b*8192 + c*256 + gy*16 + gx]  (the .view trick)
  for (int i = tid; i < 32 * 324; i += 256) {
    int c = i / 324, rr = i % 324;
    int row = rr / 18, col = rr % 18;
    int yy = y0 + row, xx = x0 + col;
    float v = 0.f;
    if ((unsigned)yy < 256u && (unsigned)xx < 256u) {
      float uy = ((float)yy + 0.5f) * (1.0f / 16.0f) - 0.5f;
      float ux = ((float)xx + 0.5f) * (1.0f / 16.0f) - 0.5f;
      float fy = floorf(uy), fx = floorf(ux);
      int iy0 = (int)fy, ix0 = (int)fx;
      float ty = uy - fy, tx = ux - fx;
      int iy0c = max(0, iy0), iy1c = min(15, iy0 + 1);
      int ix0c = max(0, ix0), ix1c = min(15, ix0 + 1);
      const float* base = lnf + b * 8192 + c * 256;
      float v00 = base[iy0c * 16 + ix0c], v01 = base[iy0c * 16 + ix1c];
      float v10 = base[iy1c * 16 + ix0c], v11 = base[iy1c * 16 + ix1c];
      v = (1.f - ty) * ((1.f - tx) * v00 + tx * v01) + ty * ((1.f - tx) * v10 + tx * v11);
    }
    comb[32 * 324 + i] = v;
  }
  __syncthreads();
  int py = tid >> 4, px = tid & 15;
  float acc[32];
#pragma unroll
  for (int o = 0; o < 32; ++o) acc[o] = gate_b[o];
  for (int ic = 0; ic < 64; ++ic) {
#pragma unroll
    for (int ky = 0; ky < 3; ++ky)
#pragma unroll
      for (int kx = 0; kx < 3; ++kx) {
        float v = comb[ic * 324 + (py + ky) * 18 + (px + kx)];
        const float* wp = wTg + (ic * 9 + ky * 3 + kx) * 32;
#pragma unroll
        for (int o = 0; o < 32; ++o) acc[o] = fmaf(v, wp[o], acc[o]);
      }
  }
  int oy = gy * 16 + py, ox = gx * 16 + px;
  int ctr = (py + 1) * 18 + (px + 1);
#pragma unroll
  for (int o = 0; o < 32; ++o) {
    float gate = sigmoidf_(acc[o]);
    float cf = comb[o * 324 + ctr];
    float gu = comb[(32 + o) * 324 + ctr];
    float merged = gate * cf + (1.0f - gate) * gu;
    float gamma = tp[b * 64 + o], beta = tp[b * 64 + 32 + o];
    out[((b * 32 + o) * 256 + oy) * 256 + ox] = merged * (gamma + 1.0f) + beta;
  }
}

extern "C" void kernel_launch(void* const* d_in, const int* in_sizes, int n_in,
                              void* d_out, int out_size, void* d_ws, size_t ws_size,
                              hipStream_t stream) {
  const float* x      = (const float*)d_in[0];
  const float* t      = (const float*)d_in[1];
  const float* conv_w = (const float*)d_in[2];
  const float* conv_b = (const float*)d_in[3];
  const float* gn_g   = (const float*)d_in[4];
  const float* gn_b   = (const float*)d_in[5];
  const float* gcn_w  = (const float*)d_in[6];
  const float* gcn_b  = (const float*)d_in[7];
  const float* ln_g   = (const float*)d_in[8];
  const float* ln_b   = (const float*)d_in[9];
  const float* gate_w = (const float*)d_in[10];
  const float* gate_b = (const float*)d_in[11];
  const float* tp_w   = (const float*)d_in[12];
  const float* tp_b   = (const float*)d_in[13];

  float* ws    = (float*)d_ws;
  float* y     = ws;                    // 33,554,432
  float* st    = ws + 33554432;         // 256 (sum[128], sumsq[128])
  float* mr    = st + 256;              // 256 (mean[128], rstd[128])
  float* nodes = mr + 256;              // 4096*34
  float* h     = nodes + 4096 * 34;     // 4096*32
  float* lnf   = h + 4096 * 32;         // 4096*32
  float* tp    = lnf + 4096 * 32;       // 1024
  float* wTc   = tp + 1024;             // 9216
  float* wTg   = wTc + 9216;            // 18432

  hipMemsetAsync(st, 0, 256 * sizeof(float), stream);
  transpose_w<<<72, 256, 0, stream>>>(conv_w, gate_w, wTc, wTg);
  conv1_kernel<<<NB * 256, 256, 0, stream>>>(x, wTc, conv_b, y, st, nodes);
  gn_finalize<<<1, 128, 0, stream>>>(st, mr);
  gcn_mm<<<512, 256, 0, stream>>>(nodes, gcn_w, h);
  gcn_prop_ln<<<2048, 64, 0, stream>>>(h, gcn_b, ln_g, ln_b, lnf);
  tproj<<<4, 256, 0, stream>>>(t, tp_w, tp_b, tp);
  fused_gate<<<NB * 256, 256, 0, stream>>>(y, mr, gn_g, gn_b, lnf, wTg, gate_b, tp,
                                           (float*)d_out);
}

// Round 4
// 310.631 us; speedup vs baseline: 8.4373x; 8.4373x over previous
//
#include <hip/hip_runtime.h>
#include <math.h>

typedef __attribute__((ext_vector_type(4))) float f32x4;
typedef __attribute__((ext_vector_type(8))) short s16x8;
typedef __attribute__((ext_vector_type(4))) short s16x4;

static __device__ __forceinline__ float sigmoidf_(float v) { return 1.0f / (1.0f + __expf(-v)); }
static __device__ __forceinline__ unsigned short f2bf(float f) {
  unsigned u = __float_as_uint(f);
  u += 0x7fffu + ((u >> 16) & 1u);      // round-to-nearest-even
  return (unsigned short)(u >> 16);
}
static __device__ __forceinline__ float bf2f(unsigned short h) {
  return __uint_as_float(((unsigned)h) << 16);
}

// K0: weights -> bf16, [tap][o][ic] layout (B-fragment rows contiguous in ic).
__global__ __launch_bounds__(256) void prep_weights(const float* __restrict__ cw,
                                                    const float* __restrict__ gw,
                                                    unsigned short* __restrict__ wcb,
                                                    unsigned short* __restrict__ wgb) {
  int i = blockIdx.x * 256 + threadIdx.x;
  if (i < 9216) {   // conv_w [o][c][3][3] -> wcb[tap][o][c=32]
    int tap = i >> 10, rem = i & 1023, o = rem >> 5, c = rem & 31;
    wcb[i] = f2bf(cw[(o * 32 + c) * 9 + tap]);
  }
  if (i < 18432) {  // gate_w [o][ic][3][3] -> wgb[tap][o][ic=64]
    int tap = i >> 11, rem = i & 2047, o = rem >> 6, c = rem & 63;
    wgb[i] = f2bf(gw[(o * 64 + c) * 9 + tap]);
  }
}

// K_nodes: per-patch means of x (f32-exact) + coords -> nodes [4096][34]
__global__ __launch_bounds__(256) void patch_nodes(const float* __restrict__ x,
                                                   float* __restrict__ nodes) {
  int blk = blockIdx.x;  // 1024 = b(16) * gy(16) * cq(4)
  int b = blk >> 6, gy = (blk >> 2) & 15, cq = blk & 3;
  int tid = threadIdx.x;
  int xcol = tid;
  for (int cc = 0; cc < 8; ++cc) {
    int c = cq * 8 + cc;
    const float* base = x + ((size_t)(b * 32 + c)) * 65536 + (gy * 16) * 256 + xcol;
    float s = 0.f;
#pragma unroll
    for (int yy = 0; yy < 16; ++yy) s += base[yy * 256];
#pragma unroll
    for (int m = 1; m < 16; m <<= 1) s += __shfl_xor(s, m);
    if ((tid & 15) == 0)
      nodes[(size_t)(b * 256 + gy * 16 + (tid >> 4)) * 34 + c] = s * (1.f / 256.f);
  }
  if (cq == 0 && tid < 16) {
    nodes[(size_t)(b * 256 + gy * 16 + tid) * 34 + 32] = (float)gy * (1.f / 16.f);
    nodes[(size_t)(b * 256 + gy * 16 + tid) * 34 + 33] = (float)tid * (1.f / 16.f);
  }
}

// K1: conv3x3 (32->32) via MFMA implicit GEMM, output y in bf16.
__global__ __launch_bounds__(256) void conv1_mfma(const float* __restrict__ x,
                                                  const unsigned short* __restrict__ wcb,
                                                  const float* __restrict__ conv_b,
                                                  unsigned short* __restrict__ ybf) {
  __shared__ alignas(16) unsigned short xt[324 * 32];  // [s][c] bf16, swizzled
  int blk = blockIdx.x;
  int b = blk >> 8, r = blk & 255, gy = r >> 4, gx = r & 15;
  int tid = threadIdx.x;
  int y0 = gy * 16 - 1, x0 = gx * 16 - 1;
  for (int i = tid; i < 2592; i += 256) {
    int q = i / 324, s = i - q * 324;
    int row = s / 18, col = s - row * 18;
    int yy = y0 + row, xx = x0 + col;
    float v0 = 0, v1 = 0, v2 = 0, v3 = 0;
    if ((unsigned)yy < 256u && (unsigned)xx < 256u) {
      const float* p = x + ((size_t)(b * 32 + q * 4)) * 65536 + yy * 256 + xx;
      v0 = p[0]; v1 = p[65536]; v2 = p[131072]; v3 = p[196608];
    }
    int slot = (q >> 1) ^ (s & 3) ^ ((s >> 2) & 3);
    int off = s * 32 + slot * 8 + (q & 1) * 4;
    s16x4 pk = { (short)f2bf(v0), (short)f2bf(v1), (short)f2bf(v2), (short)f2bf(v3) };
    *(s16x4*)&xt[off] = pk;
  }
  __syncthreads();

  int wv = tid >> 6, lane = tid & 63;
  int lr = lane & 15, lg = lane >> 4;
  f32x4 acc[4][2];
  float b0 = conv_b[lr], b1 = conv_b[16 + lr];
#pragma unroll
  for (int mi = 0; mi < 4; ++mi) {
    acc[mi][0] = (f32x4){b0, b0, b0, b0};
    acc[mi][1] = (f32x4){b1, b1, b1, b1};
  }
#pragma unroll
  for (int ky = 0; ky < 3; ++ky)
#pragma unroll
    for (int kx = 0; kx < 3; ++kx) {
      int tap = ky * 3 + kx;
      s16x8 bf0 = *(const s16x8*)&wcb[tap * 1024 + lr * 32 + lg * 8];
      s16x8 bf1 = *(const s16x8*)&wcb[tap * 1024 + (16 + lr) * 32 + lg * 8];
#pragma unroll
      for (int mi = 0; mi < 4; ++mi) {
        int s = (wv * 4 + mi + ky) * 18 + lr + kx;
        int offA = s * 32 + ((lg ^ (s & 3) ^ ((s >> 2) & 3)) << 3);
        s16x8 af = *(const s16x8*)&xt[offA];
        acc[mi][0] = __builtin_amdgcn_mfma_f32_16x16x32_bf16(af, bf0, acc[mi][0], 0, 0, 0);
        acc[mi][1] = __builtin_amdgcn_mfma_f32_16x16x32_bf16(af, bf1, acc[mi][1], 0, 0, 0);
      }
    }
#pragma unroll
  for (int mi = 0; mi < 4; ++mi) {
    int m = wv * 4 + mi;
    int oy = gy * 16 + m;
#pragma unroll
    for (int nt = 0; nt < 2; ++nt) {
      int o = nt * 16 + lr;
      f32x4 a = acc[mi][nt];
      s16x4 pk = { (short)f2bf(a[0]), (short)f2bf(a[1]), (short)f2bf(a[2]), (short)f2bf(a[3]) };
      *(s16x4*)&ybf[((size_t)(b * 32 + o)) * 65536 + oy * 256 + gx * 16 + lg * 4] = pk;
    }
  }
}

// K_stats: GN sum/sumsq per (b, group) from bf16 y.
__global__ __launch_bounds__(256) void gn_stats(const unsigned short* __restrict__ ybf,
                                                float* __restrict__ stats) {
  int blk = blockIdx.x;  // 1024 = b(16) * g(8) * slice(8)
  int b = blk >> 6, g = (blk >> 3) & 7, sl = blk & 7;
  int tid = threadIdx.x;
  float s = 0.f, q = 0.f;
  for (int cc = 0; cc < 4; ++cc) {
    const unsigned short* base = ybf + ((size_t)(b * 32 + g * 4 + cc)) * 65536 + sl * 8192;
    for (int it = 0; it < 4; ++it) {
      s16x8 v = *(const s16x8*)&base[(it * 256 + tid) * 8];
#pragma unroll
      for (int j = 0; j < 8; ++j) {
        float f = bf2f((unsigned short)v[j]);
        s += f; q += f * f;
      }
    }
  }
  for (int m = 1; m < 64; m <<= 1) { s += __shfl_xor(s, m); q += __shfl_xor(q, m); }
  __shared__ float ps[4], pq[4];
  if ((tid & 63) == 0) { ps[tid >> 6] = s; pq[tid >> 6] = q; }
  __syncthreads();
  if (tid == 0) {
    atomicAdd(&stats[b * 8 + g], ps[0] + ps[1] + ps[2] + ps[3]);
    atomicAdd(&stats[128 + b * 8 + g], pq[0] + pq[1] + pq[2] + pq[3]);
  }
}

// K2: GN mean/rstd
__global__ void gn_finalize(const float* __restrict__ stats, float* __restrict__ mr) {
  int i = threadIdx.x;  // 128
  float s = stats[i], q = stats[128 + i];
  const float n = (float)(4 * 256 * 256);
  float mean = s / n;
  float var = q / n - mean * mean;
  mr[i] = mean;
  mr[128 + i] = rsqrtf(var + 1e-5f);
}

// K3: h = nodes @ gcn_w
__global__ __launch_bounds__(256) void gcn_mm(const float* __restrict__ nodes,
                                              const float* __restrict__ gw,
                                              float* __restrict__ h) {
  int idx = blockIdx.x * 256 + threadIdx.x;
  int n = idx >> 5, o = idx & 31;
  const float* nr = nodes + n * 34;
  float s = 0.f;
#pragma unroll
  for (int k = 0; k < 34; ++k) s = fmaf(nr[k], gw[k * 32 + o], s);
  h[idx] = s;
}

__device__ __forceinline__ float dinv_at(int gy, int gx) {
  return rsqrtf((float)(1 + (gy > 0) + (gy < 15) + (gx > 0) + (gx < 15)));
}

// K4: GCN propagation + bias + LayerNorm
__global__ __launch_bounds__(64) void gcn_prop_ln(const float* __restrict__ h,
                                                  const float* __restrict__ gcn_b,
                                                  const float* __restrict__ ln_g,
                                                  const float* __restrict__ ln_b,
                                                  float* __restrict__ lnout) {
  int n = blockIdx.x * 2 + (threadIdx.x >> 5);
  int o = threadIdx.x & 31;
  int r = n & 255, gy = r >> 4, gx = r & 15;
  float dn = dinv_at(gy, gx);
  float s = h[n * 32 + o] * dn;
  if (gy > 0)  s += h[(n - 16) * 32 + o] * dinv_at(gy - 1, gx);
  if (gy < 15) s += h[(n + 16) * 32 + o] * dinv_at(gy + 1, gx);
  if (gx > 0)  s += h[(n - 1) * 32 + o] * dinv_at(gy, gx - 1);
  if (gx < 15) s += h[(n + 1) * 32 + o] * dinv_at(gy, gx + 1);
  float g = dn * s + gcn_b[o];
  float mu = g;
  for (int m = 16; m; m >>= 1) mu += __shfl_xor(mu, m);
  mu *= (1.0f / 32.0f);
  float d = g - mu;
  float v = d * d;
  for (int m = 16; m; m >>= 1) v += __shfl_xor(v, m);
  v *= (1.0f / 32.0f);
  lnout[n * 32 + o] = d * rsqrtf(v + 1e-5f) * ln_g[o] + ln_b[o];
}

// K5: tp = t @ tp_w^T + tp_b
__global__ __launch_bounds__(256) void tproj(const float* __restrict__ t,
                                             const float* __restrict__ tw,
                                             const float* __restrict__ tb,
                                             float* __restrict__ tpo) {
  int idx = blockIdx.x * 256 + threadIdx.x;
  int b = idx >> 6, j = idx & 63;
  const float* tr = t + b * 256;
  const float* wr = tw + j * 256;
  float s = tb[j];
  for (int k = 0; k < 256; ++k) s = fmaf(tr[k], wr[k], s);
  tpo[idx] = s;
}

// K6: GN+SiLU on load + bilinear upsample -> LDS (channel-last bf16, swizzled),
// gate conv via MFMA, sigmoid-merge, FiLM, store f32.
__global__ __launch_bounds__(256, 3) void fused_gate_mfma(
    const unsigned short* __restrict__ ybf, const float* __restrict__ mr,
    const float* __restrict__ gn_g, const float* __restrict__ gn_b,
    const float* __restrict__ lnf, const unsigned short* __restrict__ wgb,
    const float* __restrict__ gate_b, const float* __restrict__ tpv,
    float* __restrict__ out) {
  __shared__ alignas(16) unsigned short comb[324 * 64];  // [s][ic] bf16, swizzled
  __shared__ float g3[9 * 32];                            // 3x3 grid cells x 32c
  int blk = blockIdx.x;
  int b = blk >> 8, r = blk & 255, gy = r >> 4, gx = r & 15;
  int tid = threadIdx.x;
  // FIX (R2/R3 bug): cover all 288 entries with a strided loop; block has 256 threads.
  for (int i = tid; i < 288; i += 256) {
    int cell = i >> 5, c = i & 31;
    int dy = cell / 3, dx = cell - dy * 3;
    int gyc = min(15, max(0, gy - 1 + dy));
    int gxc = min(15, max(0, gx - 1 + dx));
    g3[cell * 32 + c] = lnf[((size_t)b) * 8192 + c * 256 + gyc * 16 + gxc];
  }
  __syncthreads();
  int y0 = gy * 16 - 1, x0 = gx * 16 - 1;
  // conv_feat half (ic 0..31): GN+SiLU on load
  for (int i = tid; i < 2592; i += 256) {
    int q = i / 324, s = i - q * 324;
    int row = s / 18, col = s - row * 18;
    int yy = y0 + row, xx = x0 + col;
    float v[4] = {0.f, 0.f, 0.f, 0.f};
    if ((unsigned)yy < 256u && (unsigned)xx < 256u) {
      int c0 = q * 4;
      const unsigned short* p = ybf + ((size_t)(b * 32 + c0)) * 65536 + yy * 256 + xx;
#pragma unroll
      for (int j = 0; j < 4; ++j) {
        int c = c0 + j, gg = c >> 2;
        float f = bf2f(p[j * 65536]);
        f = (f - mr[b * 8 + gg]) * mr[128 + b * 8 + gg];
        f = f * gn_g[c] + gn_b[c];
        v[j] = f * sigmoidf_(f);
      }
    }
    int off = s * 64 + (((q >> 1) ^ (s & 7)) << 3) + (q & 1) * 4;
    s16x4 pk = { (short)f2bf(v[0]), (short)f2bf(v[1]), (short)f2bf(v[2]), (short)f2bf(v[3]) };
    *(s16x4*)&comb[off] = pk;
  }
  // gcn_up half (ic 32..63): bilinear from g3
  for (int i = tid; i < 2592; i += 256) {
    int q = i / 324, s = i - q * 324;
    int row = s / 18, col = s - row * 18;
    int yy = y0 + row, xx = x0 + col;
    float v[4] = {0.f, 0.f, 0.f, 0.f};
    if ((unsigned)yy < 256u && (unsigned)xx < 256u) {
      float uy = ((float)yy + 0.5f) * (1.f / 16.f) - 0.5f;
      float ux = ((float)xx + 0.5f) * (1.f / 16.f) - 0.5f;
      float fy = floorf(uy), fx = floorf(ux);
      float ty = uy - fy, tx = ux - fx;
      int dy0 = (int)fy - (gy - 1), dx0 = (int)fx - (gx - 1);  // in {0,1}
      const float* g00 = &g3[(dy0 * 3 + dx0) * 32 + q * 4];
      float w00 = (1.f - ty) * (1.f - tx), w01 = (1.f - ty) * tx;
      float w10 = ty * (1.f - tx), w11 = ty * tx;
#pragma unroll
      for (int j = 0; j < 4; ++j)
        v[j] = w00 * g00[j] + w01 * g00[32 + j] + w10 * g00[96 + j] + w11 * g00[128 + j];
    }
    int qq = q + 8;
    int off = s * 64 + (((qq >> 1) ^ (s & 7)) << 3) + (qq & 1) * 4;
    s16x4 pk = { (short)f2bf(v[0]), (short)f2bf(v[1]), (short)f2bf(v[2]), (short)f2bf(v[3]) };
    *(s16x4*)&comb[off] = pk;
  }
  __syncthreads();

  int wv = tid >> 6, lane = tid & 63;
  int lr = lane & 15, lg = lane >> 4;
  f32x4 acc[4][2];
  float b0 = gate_b[lr], b1 = gate_b[16 + lr];
#pragma unroll
  for (int mi = 0; mi < 4; ++mi) {
    acc[mi][0] = (f32x4){b0, b0, b0, b0};
    acc[mi][1] = (f32x4){b1, b1, b1, b1};
  }
#pragma unroll
  for (int ky = 0; ky < 3; ++ky)
#pragma unroll
    for (int kx = 0; kx < 3; ++kx) {
      int tap = ky * 3 + kx;
      const unsigned short* wb = wgb + tap * 2048;
      s16x8 bf00 = *(const s16x8*)&wb[lr * 64 + lg * 8];
      s16x8 bf01 = *(const s16x8*)&wb[lr * 64 + 32 + lg * 8];
      s16x8 bf10 = *(const s16x8*)&wb[(16 + lr) * 64 + lg * 8];
      s16x8 bf11 = *(const s16x8*)&wb[(16 + lr) * 64 + 32 + lg * 8];
#pragma unroll
      for (int mi = 0; mi < 4; ++mi) {
        int s = (wv * 4 + mi + ky) * 18 + lr + kx;
        int base = s * 64;
        s16x8 a0 = *(const s16x8*)&comb[base + ((lg ^ (s & 7)) << 3)];
        s16x8 a1 = *(const s16x8*)&comb[base + (((4 + lg) ^ (s & 7)) << 3)];
        acc[mi][0] = __builtin_amdgcn_mfma_f32_16x16x32_bf16(a0, bf00, acc[mi][0], 0, 0, 0);
        acc[mi][0] = __builtin_amdgcn_mfma_f32_16x16x32_bf16(a1, bf01, acc[mi][0], 0, 0, 0);
        acc[mi][1] = __builtin_amdgcn_mfma_f32_16x16x32_bf16(a0, bf10, acc[mi][1], 0, 0, 0);
        acc[mi][1] = __builtin_amdgcn_mfma_f32_16x16x32_bf16(a1, bf11, acc[mi][1], 0, 0, 0);
      }
    }
#pragma unroll
  for (int mi = 0; mi < 4; ++mi) {
    int m = wv * 4 + mi;
#pragma unroll
    for (int nt = 0; nt < 2; ++nt) {
      int o = nt * 16 + lr;
      f32x4 a = acc[mi][nt];
      float gamma = tpv[b * 64 + o] + 1.0f, beta = tpv[b * 64 + 32 + o];
      f32x4 res;
#pragma unroll
      for (int rr = 0; rr < 4; ++rr) {
        int px = lg * 4 + rr;
        int s = (m + 1) * 18 + px + 1;
        float cf = bf2f(comb[s * 64 + (((o >> 3) ^ (s & 7)) << 3) + (o & 7)]);
        float gu = bf2f(comb[s * 64 + ((((o >> 3) + 4) ^ (s & 7)) << 3) + (o & 7)]);
        float gate = sigmoidf_(a[rr]);
        float merged = gate * cf + (1.f - gate) * gu;
        res[rr] = merged * gamma + beta;
      }
      *(f32x4*)&out[((size_t)(b * 32 + o)) * 65536 + (gy * 16 + m) * 256 + gx * 16 + lg * 4] = res;
    }
  }
}

extern "C" void kernel_launch(void* const* d_in, const int* in_sizes, int n_in,
                              void* d_out, int out_size, void* d_ws, size_t ws_size,
                              hipStream_t stream) {
  const float* x      = (const float*)d_in[0];
  const float* t      = (const float*)d_in[1];
  const float* conv_w = (const float*)d_in[2];
  const float* conv_b = (const float*)d_in[3];
  const float* gn_g   = (const float*)d_in[4];
  const float* gn_b   = (const float*)d_in[5];
  const float* gcn_w  = (const float*)d_in[6];
  const float* gcn_b  = (const float*)d_in[7];
  const float* ln_g   = (const float*)d_in[8];
  const float* ln_b   = (const float*)d_in[9];
  const float* gate_w = (const float*)d_in[10];
  const float* gate_b = (const float*)d_in[11];
  const float* tp_w   = (const float*)d_in[12];
  const float* tp_b   = (const float*)d_in[13];

  float* ws = (float*)d_ws;
  unsigned short* ybf = (unsigned short*)ws;        // 33,554,432 shorts
  float* st    = ws + 16777216;                     // 256
  float* mr    = st + 256;                          // 256
  float* nodes = mr + 256;                          // 139,264
  float* h     = nodes + 139264;                    // 131,072
  float* lnf   = h + 131072;                        // 131,072
  float* tpv   = lnf + 131072;                      // 1,024
  unsigned short* wcb = (unsigned short*)(tpv + 1024);   // 9,216 shorts
  unsigned short* wgb = wcb + 9216;                 // 18,432 shorts

  hipMemsetAsync(st, 0, 256 * sizeof(float), stream);
  prep_weights<<<72, 256, 0, stream>>>(conv_w, gate_w, wcb, wgb);
  patch_nodes<<<1024, 256, 0, stream>>>(x, nodes);
  conv1_mfma<<<4096, 256, 0, stream>>>(x, wcb, conv_b, ybf);
  gn_stats<<<1024, 256, 0, stream>>>(ybf, st);
  gn_finalize<<<1, 128, 0, stream>>>(st, mr);
  gcn_mm<<<512, 256, 0, stream>>>(nodes, gcn_w, h);
  gcn_prop_ln<<<2048, 64, 0, stream>>>(h, gcn_b, ln_g, ln_b, lnf);
  tproj<<<4, 256, 0, stream>>>(t, tp_w, tp_b, tpv);
  fused_gate_mfma<<<4096, 256, 0, stream>>>(ybf, mr, gn_g, gn_b, lnf, wgb, gate_b, tpv,
                                            (float*)d_out);
}

// Round 5
// 291.901 us; speedup vs baseline: 8.9787x; 1.0642x over previous
//
#include <hip/hip_runtime.h>
#include <math.h>

typedef __attribute__((ext_vector_type(4))) float f32x4;
typedef __attribute__((ext_vector_type(8))) short s16x8;
typedef __attribute__((ext_vector_type(4))) short s16x4;

static __device__ __forceinline__ float sigmoidf_(float v) { return 1.0f / (1.0f + __expf(-v)); }
static __device__ __forceinline__ unsigned short f2bf(float f) {
  unsigned u = __float_as_uint(f);
  u += 0x7fffu + ((u >> 16) & 1u);      // round-to-nearest-even
  return (unsigned short)(u >> 16);
}
static __device__ __forceinline__ float bf2f(unsigned short h) {
  return __uint_as_float(((unsigned)h) << 16);
}

// K0: weights -> bf16, [tap][o][ic] layout (MFMA fragment rows contiguous in ic).
__global__ __launch_bounds__(256) void prep_weights(const float* __restrict__ cw,
                                                    const float* __restrict__ gw,
                                                    unsigned short* __restrict__ wcb,
                                                    unsigned short* __restrict__ wgb) {
  int i = blockIdx.x * 256 + threadIdx.x;
  if (i < 9216) {   // conv_w [o][c][3][3] -> wcb[tap][o][c=32]
    int tap = i >> 10, rem = i & 1023, o = rem >> 5, c = rem & 31;
    wcb[i] = f2bf(cw[(o * 32 + c) * 9 + tap]);
  }
  if (i < 18432) {  // gate_w [o][ic][3][3] -> wgb[tap][o][ic=64]
    int tap = i >> 11, rem = i & 2047, o = rem >> 6, c = rem & 63;
    wgb[i] = f2bf(gw[(o * 64 + c) * 9 + tap]);
  }
}

// K1: conv3x3 (32->32) MFMA implicit GEMM (A=weights, B=pixels).
// Outputs: ycl = conv+bias, bf16, CHANNEL-LAST [b][y][x][c];
//          nodes (patch means from LDS tile); stats (GN sum/sumsq via atomics).
__global__ __launch_bounds__(256) void conv1_mfma(const float* __restrict__ x,
                                                  const unsigned short* __restrict__ wcb,
                                                  const float* __restrict__ conv_b,
                                                  unsigned short* __restrict__ ycl,
                                                  float* __restrict__ stats,
                                                  float* __restrict__ nodes) {
  __shared__ alignas(16) unsigned short xt[324 * 32];  // [s][c] bf16, swizzled
  __shared__ float gpart[8][2][4];
  int blk = blockIdx.x;
  int b = blk >> 8, r = blk & 255, gy = r >> 4, gx = r & 15;
  int tid = threadIdx.x;
  int y0 = gy * 16 - 1, x0 = gx * 16 - 1;
  for (int i = tid; i < 2592; i += 256) {
    int q = i / 324, s = i - q * 324;
    int row = s / 18, col = s - row * 18;
    int yy = y0 + row, xx = x0 + col;
    float v0 = 0, v1 = 0, v2 = 0, v3 = 0;
    if ((unsigned)yy < 256u && (unsigned)xx < 256u) {
      const float* p = x + ((size_t)(b * 32 + q * 4)) * 65536 + yy * 256 + xx;
      v0 = p[0]; v1 = p[65536]; v2 = p[131072]; v3 = p[196608];
    }
    int slot = (q >> 1) ^ (s & 3) ^ ((s >> 2) & 3);
    int off = s * 32 + slot * 8 + (q & 1) * 4;
    s16x4 pk = { (short)f2bf(v0), (short)f2bf(v1), (short)f2bf(v2), (short)f2bf(v3) };
    *(s16x4*)&xt[off] = pk;
  }
  __syncthreads();

  int wv = tid >> 6, lane = tid & 63;
  int lr = lane & 15, lg = lane >> 4;

  // fused patch means: wave wv handles channels wv*8..wv*8+7, lane sums 4 pixels
#pragma unroll
  for (int cc = 0; cc < 8; ++cc) {
    int c = wv * 8 + cc;
    int q = c >> 2, jj = c & 3;
    float s = 0.f;
#pragma unroll
    for (int pp = 0; pp < 4; ++pp) {
      int p = lane * 4 + pp;
      int sp = ((p >> 4) + 1) * 18 + (p & 15) + 1;
      int off = sp * 32 + (((q >> 1) ^ (sp & 3) ^ ((sp >> 2) & 3)) << 3) + (q & 1) * 4 + jj;
      s += bf2f(xt[off]);
    }
    for (int m = 1; m < 64; m <<= 1) s += __shfl_xor(s, m);
    if (lane == 0) nodes[(size_t)blk * 34 + c] = s * (1.f / 256.f);
  }
  if (tid == 0) {
    nodes[(size_t)blk * 34 + 32] = (float)gy * (1.f / 16.f);
    nodes[(size_t)blk * 34 + 33] = (float)gx * (1.f / 16.f);
  }

  // MFMA: A = weights (row=o), B = pixels (col=px). D: row(lg*4+rr)=o, col(lr)=px.
  f32x4 acc[4][2];
  f32x4 cb0 = *(const f32x4*)&conv_b[lg * 4];
  f32x4 cb1 = *(const f32x4*)&conv_b[16 + lg * 4];
#pragma unroll
  for (int mi = 0; mi < 4; ++mi) { acc[mi][0] = cb0; acc[mi][1] = cb1; }
#pragma unroll
  for (int ky = 0; ky < 3; ++ky)
#pragma unroll
    for (int kx = 0; kx < 3; ++kx) {
      int tap = ky * 3 + kx;
      s16x8 wf0 = *(const s16x8*)&wcb[tap * 1024 + lr * 32 + lg * 8];        // o=lr
      s16x8 wf1 = *(const s16x8*)&wcb[tap * 1024 + (16 + lr) * 32 + lg * 8]; // o=16+lr
#pragma unroll
      for (int mi = 0; mi < 4; ++mi) {
        int s = (wv * 4 + mi + ky) * 18 + lr + kx;
        int offB = s * 32 + ((lg ^ (s & 3) ^ ((s >> 2) & 3)) << 3);
        s16x8 xf = *(const s16x8*)&xt[offB];
        acc[mi][0] = __builtin_amdgcn_mfma_f32_16x16x32_bf16(wf0, xf, acc[mi][0], 0, 0, 0);
        acc[mi][1] = __builtin_amdgcn_mfma_f32_16x16x32_bf16(wf1, xf, acc[mi][1], 0, 0, 0);
      }
    }
  // epilogue: channel-last store; lane holds o = nt*16+lg*4+rr at pixel col lr
#pragma unroll
  for (int mi = 0; mi < 4; ++mi) {
    int oy = gy * 16 + wv * 4 + mi;
    size_t pixbase = ((size_t)b * 65536 + (size_t)oy * 256 + gx * 16 + lr) * 32;
#pragma unroll
    for (int nt = 0; nt < 2; ++nt) {
      f32x4 a = acc[mi][nt];
      s16x4 pk = { (short)f2bf(a[0]), (short)f2bf(a[1]), (short)f2bf(a[2]), (short)f2bf(a[3]) };
      *(s16x4*)&ycl[pixbase + nt * 16 + lg * 4] = pk;
    }
  }
  // fused GN stats: group g = nt*4+lg (all 4 regs of acc[*][nt] in same group)
#pragma unroll
  for (int nt = 0; nt < 2; ++nt) {
    float s = 0.f, q = 0.f;
#pragma unroll
    for (int mi = 0; mi < 4; ++mi)
#pragma unroll
      for (int rr = 0; rr < 4; ++rr) {
        float v = acc[mi][nt][rr];
        s += v; q += v * v;
      }
    for (int m = 1; m < 16; m <<= 1) { s += __shfl_xor(s, m); q += __shfl_xor(q, m); }
    if (lr == 0) { gpart[nt * 4 + lg][0][wv] = s; gpart[nt * 4 + lg][1][wv] = q; }
  }
  __syncthreads();
  if (tid < 16) {
    int g = tid >> 1, which = tid & 1;
    float v = gpart[g][which][0] + gpart[g][which][1] + gpart[g][which][2] + gpart[g][which][3];
    atomicAdd(&stats[(which ? 128 : 0) + b * 8 + g], v);
  }
}

// K2: fold GN into per-(b,c) scale/shift
__global__ void gn_finalize(const float* __restrict__ stats,
                            const float* __restrict__ gn_g,
                            const float* __restrict__ gn_b,
                            float* __restrict__ mrs) {
  int i = threadIdx.x;  // 512
  int b = i >> 5, c = i & 31, g = c >> 2;
  float s = stats[b * 8 + g], q = stats[128 + b * 8 + g];
  const float n = 262144.f;
  float mean = s / n;
  float var = q / n - mean * mean;
  float rs = rsqrtf(var + 1e-5f);
  float scale = rs * gn_g[c];
  mrs[i] = scale;
  mrs[512 + i] = gn_b[c] - mean * scale;
}

// K2b: in-place GN+SiLU over channel-last y (elementwise, vectorized)
__global__ __launch_bounds__(256) void gn_apply(unsigned short* __restrict__ ycl,
                                                const float* __restrict__ mrs) {
  int i = blockIdx.x * 256 + threadIdx.x;   // octet id; grid covers 16*65536*4 exactly
  int b = i >> 18, oct = i & 3;
  f32x4 sc0 = *(const f32x4*)&mrs[b * 32 + oct * 8];
  f32x4 sc1 = *(const f32x4*)&mrs[b * 32 + oct * 8 + 4];
  f32x4 sh0 = *(const f32x4*)&mrs[512 + b * 32 + oct * 8];
  f32x4 sh1 = *(const f32x4*)&mrs[512 + b * 32 + oct * 8 + 4];
  s16x8 v = *(const s16x8*)&ycl[(size_t)i * 8];
  s16x8 rr;
#pragma unroll
  for (int j = 0; j < 8; ++j) {
    float sc = j < 4 ? sc0[j] : sc1[j - 4];
    float sh = j < 4 ? sh0[j] : sh1[j - 4];
    float f = bf2f((unsigned short)v[j]) * sc + sh;
    f = f * sigmoidf_(f);
    rr[j] = (short)f2bf(f);
  }
  *(s16x8*)&ycl[(size_t)i * 8] = rr;
}

// K3: h = nodes @ gcn_w
__global__ __launch_bounds__(256) void gcn_mm(const float* __restrict__ nodes,
                                              const float* __restrict__ gw,
                                              float* __restrict__ h) {
  int idx = blockIdx.x * 256 + threadIdx.x;
  int n = idx >> 5, o = idx & 31;
  const float* nr = nodes + n * 34;
  float s = 0.f;
#pragma unroll
  for (int k = 0; k < 34; ++k) s = fmaf(nr[k], gw[k * 32 + o], s);
  h[idx] = s;
}

__device__ __forceinline__ float dinv_at(int gy, int gx) {
  return rsqrtf((float)(1 + (gy > 0) + (gy < 15) + (gx > 0) + (gx < 15)));
}

// K4: GCN propagation + bias + LayerNorm
__global__ __launch_bounds__(64) void gcn_prop_ln(const float* __restrict__ h,
                                                  const float* __restrict__ gcn_b,
                                                  const float* __restrict__ ln_g,
                                                  const float* __restrict__ ln_b,
                                                  float* __restrict__ lnout) {
  int n = blockIdx.x * 2 + (threadIdx.x >> 5);
  int o = threadIdx.x & 31;
  int r = n & 255, gy = r >> 4, gx = r & 15;
  float dn = dinv_at(gy, gx);
  float s = h[n * 32 + o] * dn;
  if (gy > 0)  s += h[(n - 16) * 32 + o] * dinv_at(gy - 1, gx);
  if (gy < 15) s += h[(n + 16) * 32 + o] * dinv_at(gy + 1, gx);
  if (gx > 0)  s += h[(n - 1) * 32 + o] * dinv_at(gy, gx - 1);
  if (gx < 15) s += h[(n + 1) * 32 + o] * dinv_at(gy, gx + 1);
  float g = dn * s + gcn_b[o];
  float mu = g;
  for (int m = 16; m; m >>= 1) mu += __shfl_xor(mu, m);
  mu *= (1.0f / 32.0f);
  float d = g - mu;
  float v = d * d;
  for (int m = 16; m; m >>= 1) v += __shfl_xor(v, m);
  v *= (1.0f / 32.0f);
  lnout[n * 32 + o] = d * rsqrtf(v + 1e-5f) * ln_g[o] + ln_b[o];
}

// K5: tp = t @ tp_w^T + tp_b
__global__ __launch_bounds__(256) void tproj(const float* __restrict__ t,
                                             const float* __restrict__ tw,
                                             const float* __restrict__ tb,
                                             float* __restrict__ tpo) {
  int idx = blockIdx.x * 256 + threadIdx.x;
  int b = idx >> 6, j = idx & 63;
  const float* tr = t + b * 256;
  const float* wr = tw + j * 256;
  float s = tb[j];
  for (int k = 0; k < 256; ++k) s = fmaf(tr[k], wr[k], s);
  tpo[idx] = s;
}

// K6: staging = vector copy (conv half) + separable bilinear (gcn half);
// gate conv via MFMA; sigmoid-merge; FiLM; store f32.
__global__ __launch_bounds__(256, 3) void fused_gate_mfma(
    const unsigned short* __restrict__ ycl, const float* __restrict__ lnf,
    const unsigned short* __restrict__ wgb, const float* __restrict__ gate_b,
    const float* __restrict__ tpv, float* __restrict__ out) {
  __shared__ alignas(16) unsigned short comb[324 * 64];  // [s][ic] bf16, swizzled
  __shared__ float vv[18 * 3 * 32];                       // vertical-interp grid
  int blk = blockIdx.x;
  int b = blk >> 8, r = blk & 255, gy = r >> 4, gx = r & 15;
  int tid = threadIdx.x;
  int y0 = gy * 16 - 1, x0 = gx * 16 - 1;

  // vertical bilinear interp: vv[row][xc][c]
  for (int i = tid; i < 1728; i += 256) {
    int row = i / 96, rem = i - row * 96, xc = rem >> 5, c = rem & 31;
    int yy = y0 + row;
    float uy = ((float)yy + 0.5f) * (1.f / 16.f) - 0.5f;
    float fy = floorf(uy);
    float ty = uy - fy;
    int iy0 = (int)fy;
    int iy0c = max(0, iy0), iy1c = min(15, iy0 + 1);
    int gxx = min(15, max(0, gx - 1 + xc));
    const float* base = lnf + (size_t)b * 8192 + c * 256;
    float v0 = base[iy0c * 16 + gxx], v1 = base[iy1c * 16 + gxx];
    vv[i] = v0 + ty * (v1 - v0);
  }

  // conv half: straight vector copy from channel-last silu'd y
  for (int i = tid; i < 324; i += 256) {
    int row = i / 18, col = i - row * 18;
    int yy = y0 + row, xx = x0 + col;
    bool in = ((unsigned)yy < 256u) && ((unsigned)xx < 256u);
    const unsigned short* p = ycl + ((size_t)b * 65536 + (size_t)yy * 256 + xx) * 32;
    int sw = i & 7;
#pragma unroll
    for (int h = 0; h < 4; ++h) {
      s16x8 v = in ? *(const s16x8*)&p[h * 8] : (s16x8){0, 0, 0, 0, 0, 0, 0, 0};
      *(s16x8*)&comb[i * 64 + ((h ^ sw) << 3)] = v;
    }
  }
  __syncthreads();

  // gcn half: horizontal interp from vv
  for (int i = tid; i < 324; i += 256) {
    int row = i / 18, col = i - row * 18;
    int yy = y0 + row, xx = x0 + col;
    int sw = i & 7;
    if (((unsigned)yy < 256u) && ((unsigned)xx < 256u)) {
      float ux = ((float)xx + 0.5f) * (1.f / 16.f) - 0.5f;
      float fx = floorf(ux);
      float tx = ux - fx;
      int dx0 = (int)fx - (gx - 1);   // in {0,1}
      const float* va = &vv[(row * 3 + dx0) * 32];
      const float* vb = va + 32;
#pragma unroll
      for (int h = 0; h < 4; ++h) {
        s16x8 pk;
#pragma unroll
        for (int j = 0; j < 8; ++j) {
          float a = va[h * 8 + j];
          pk[j] = (short)f2bf(a + tx * (vb[h * 8 + j] - a));
        }
        *(s16x8*)&comb[i * 64 + (((4 + h) ^ sw) << 3)] = pk;
      }
    } else {
      s16x8 z = (s16x8){0, 0, 0, 0, 0, 0, 0, 0};
#pragma unroll
      for (int h = 0; h < 4; ++h) *(s16x8*)&comb[i * 64 + (((4 + h) ^ sw) << 3)] = z;
    }
  }
  __syncthreads();

  int wv = tid >> 6, lane = tid & 63;
  int lr = lane & 15, lg = lane >> 4;
  f32x4 acc[4][2];
  float b0 = gate_b[lr], b1 = gate_b[16 + lr];
#pragma unroll
  for (int mi = 0; mi < 4; ++mi) {
    acc[mi][0] = (f32x4){b0, b0, b0, b0};
    acc[mi][1] = (f32x4){b1, b1, b1, b1};
  }
#pragma unroll
  for (int ky = 0; ky < 3; ++ky)
#pragma unroll
    for (int kx = 0; kx < 3; ++kx) {
      int tap = ky * 3 + kx;
      const unsigned short* wb = wgb + tap * 2048;
      s16x8 bf00 = *(const s16x8*)&wb[lr * 64 + lg * 8];
      s16x8 bf01 = *(const s16x8*)&wb[lr * 64 + 32 + lg * 8];
      s16x8 bf10 = *(const s16x8*)&wb[(16 + lr) * 64 + lg * 8];
      s16x8 bf11 = *(const s16x8*)&wb[(16 + lr) * 64 + 32 + lg * 8];
#pragma unroll
      for (int mi = 0; mi < 4; ++mi) {
        int s = (wv * 4 + mi + ky) * 18 + lr + kx;
        int base = s * 64;
        s16x8 a0 = *(const s16x8*)&comb[base + ((lg ^ (s & 7)) << 3)];
        s16x8 a1 = *(const s16x8*)&comb[base + (((4 + lg) ^ (s & 7)) << 3)];
        acc[mi][0] = __builtin_amdgcn_mfma_f32_16x16x32_bf16(a0, bf00, acc[mi][0], 0, 0, 0);
        acc[mi][0] = __builtin_amdgcn_mfma_f32_16x16x32_bf16(a1, bf01, acc[mi][0], 0, 0, 0);
        acc[mi][1] = __builtin_amdgcn_mfma_f32_16x16x32_bf16(a0, bf10, acc[mi][1], 0, 0, 0);
        acc[mi][1] = __builtin_amdgcn_mfma_f32_16x16x32_bf16(a1, bf11, acc[mi][1], 0, 0, 0);
      }
    }
#pragma unroll
  for (int mi = 0; mi < 4; ++mi) {
    int m = wv * 4 + mi;
#pragma unroll
    for (int nt = 0; nt < 2; ++nt) {
      int o = nt * 16 + lr;
      f32x4 a = acc[mi][nt];
      float gamma = tpv[b * 64 + o] + 1.0f, beta = tpv[b * 64 + 32 + o];
      f32x4 res;
#pragma unroll
      for (int rr = 0; rr < 4; ++rr) {
        int px = lg * 4 + rr;
        int s = (m + 1) * 18 + px + 1;
        float cf = bf2f(comb[s * 64 + (((o >> 3) ^ (s & 7)) << 3) + (o & 7)]);
        float gu = bf2f(comb[s * 64 + ((((o >> 3) + 4) ^ (s & 7)) << 3) + (o & 7)]);
        float gate = sigmoidf_(a[rr]);
        float merged = gate * cf + (1.f - gate) * gu;
        res[rr] = merged * gamma + beta;
      }
      *(f32x4*)&out[((size_t)(b * 32 + o)) * 65536 + (size_t)(gy * 16 + m) * 256 + gx * 16 + lg * 4] = res;
    }
  }
}

extern "C" void kernel_launch(void* const* d_in, const int* in_sizes, int n_in,
                              void* d_out, int out_size, void* d_ws, size_t ws_size,
                              hipStream_t stream) {
  const float* x      = (const float*)d_in[0];
  const float* t      = (const float*)d_in[1];
  const float* conv_w = (const float*)d_in[2];
  const float* conv_b = (const float*)d_in[3];
  const float* gn_g   = (const float*)d_in[4];
  const float* gn_b   = (const float*)d_in[5];
  const float* gcn_w  = (const float*)d_in[6];
  const float* gcn_b  = (const float*)d_in[7];
  const float* ln_g   = (const float*)d_in[8];
  const float* ln_b   = (const float*)d_in[9];
  const float* gate_w = (const float*)d_in[10];
  const float* gate_b = (const float*)d_in[11];
  const float* tp_w   = (const float*)d_in[12];
  const float* tp_b   = (const float*)d_in[13];

  float* ws = (float*)d_ws;
  unsigned short* ycl = (unsigned short*)ws;        // 33,554,432 u16 (channel-last y)
  float* st    = ws + 16777216;                     // 256
  float* mrs   = st + 256;                          // 1024 (scale 512, shift 512)
  float* nodes = mrs + 1024;                        // 139,264
  float* h     = nodes + 139264;                    // 131,072
  float* lnf   = h + 131072;                        // 131,072
  float* tpv   = lnf + 131072;                      // 1,024
  unsigned short* wcb = (unsigned short*)(tpv + 1024);   // 9,216 u16
  unsigned short* wgb = wcb + 9216;                 // 18,432 u16

  hipMemsetAsync(st, 0, 256 * sizeof(float), stream);
  prep_weights<<<72, 256, 0, stream>>>(conv_w, gate_w, wcb, wgb);
  conv1_mfma<<<4096, 256, 0, stream>>>(x, wcb, conv_b, ycl, st, nodes);
  gn_finalize<<<1, 512, 0, stream>>>(st, gn_g, gn_b, mrs);
  gn_apply<<<16384, 256, 0, stream>>>(ycl, mrs);
  gcn_mm<<<512, 256, 0, stream>>>(nodes, gcn_w, h);
  gcn_prop_ln<<<2048, 64, 0, stream>>>(h, gcn_b, ln_g, ln_b, lnf);
  tproj<<<4, 256, 0, stream>>>(t, tp_w, tp_b, tpv);
  fused_gate_mfma<<<4096, 256, 0, stream>>>(ycl, lnf, wgb, gate_b, tpv, (float*)d_out);
}